// Round 4
// baseline (962.530 us; speedup 1.0000x reference)
//
#include <hip/hip_runtime.h>
#include <math.h>

// Problem constants
#define B_   8
#define H_   128
#define W_   128
#define C_   256
#define WS_  8
#define SS_  4
#define NH_  8
#define HD_  32
#define MROWS 131072   // B * H * W tokens

typedef short bf16x8 __attribute__((ext_vector_type(8)));
typedef float f32x4  __attribute__((ext_vector_type(4)));

__device__ __forceinline__ unsigned short f2bf(float f) {
    unsigned int u = __float_as_uint(f);
    u += 0x7fffu + ((u >> 16) & 1u);          // round-to-nearest-even
    return (unsigned short)(u >> 16);
}

// async global->LDS, 16 bytes per lane; lds dest = wave-uniform base + lane*16
__device__ __forceinline__ void gload16(const unsigned short* g, unsigned short* l) {
    __builtin_amdgcn_global_load_lds(
        (const __attribute__((address_space(1))) unsigned int*)(const void*)g,
        (__attribute__((address_space(3))) unsigned int*)(void*)l, 16, 0, 0);
}

// fast exact-GELU: erf via Abramowitz-Stegun 7.1.26 (|err| <= 1.5e-7)
__device__ __forceinline__ float fast_gelu(float v) {
    const float x  = v * 0.70710678118654752f;
    const float ax = fabsf(x);
    const float t  = __builtin_amdgcn_rcpf(fmaf(0.3275911f, ax, 1.0f));
    float p = fmaf(1.061405429f, t, -1.453152027f);
    p = fmaf(p, t, 1.421413741f);
    p = fmaf(p, t, -0.284496736f);
    p = fmaf(p, t, 0.254829592f);
    p *= t;
    const float e  = __expf(-ax * ax);
    const float er = copysignf(1.0f - p * e, x);
    return 0.5f * v * (1.0f + er);
}

// ---------------------------------------------------------------------------
// fp32 -> bf16 weight conversion
// ---------------------------------------------------------------------------
__global__ __launch_bounds__(256) void cvt4(const float* __restrict__ s,
                                            unsigned short* __restrict__ d, int n) {
    const int i = (blockIdx.x * 256 + threadIdx.x) * 4;
    if (i >= n) return;
    const float4 v = *(const float4*)(s + i);
    ushort4 o;
    o.x = f2bf(v.x); o.y = f2bf(v.y); o.z = f2bf(v.z); o.w = f2bf(v.w);
    *(ushort4*)(d + i) = o;
}

// ---------------------------------------------------------------------------
// LayerNorm: one wave per token, 4 channels/lane. fp32 in -> bf16 out.
// SHIFT=1: dest row is (shifted frame, window-partition) layout.
// ---------------------------------------------------------------------------
template<int SHIFT>
__global__ __launch_bounds__(256) void ln_kernel(const float* __restrict__ in,
                                                 const float* __restrict__ g,
                                                 const float* __restrict__ b,
                                                 unsigned short* __restrict__ out) {
    const int wid  = threadIdx.x >> 6;
    const int lane = threadIdx.x & 63;
    const int row  = blockIdx.x * 4 + wid;

    int src;
    if (SHIFT) {
        const int bimg = row >> 14;
        const int rem  = row & 16383;
        const int win  = rem >> 6;
        const int tok  = rem & 63;
        const int hp = (win >> 4) * 8 + (tok >> 3);
        const int wp = (win & 15) * 8 + (tok & 7);
        const int ho = (hp + SS_) & (H_ - 1);
        const int wo = (wp + SS_) & (W_ - 1);
        src = (bimg << 14) + ho * W_ + wo;
    } else {
        src = row;
    }

    const float4 v = ((const float4*)(in + (size_t)src * C_))[lane];
    float s  = v.x + v.y + v.z + v.w;
    float ss = v.x*v.x + v.y*v.y + v.z*v.z + v.w*v.w;
#pragma unroll
    for (int o = 1; o < 64; o <<= 1) {
        s  += __shfl_xor(s,  o, 64);
        ss += __shfl_xor(ss, o, 64);
    }
    const float mean = s * (1.0f / C_);
    const float var  = ss * (1.0f / C_) - mean * mean;
    const float rstd = rsqrtf(var + 1e-5f);

    const float4 gg = ((const float4*)g)[lane];
    const float4 bb = ((const float4*)b)[lane];
    ushort4 o4;
    o4.x = f2bf((v.x - mean) * rstd * gg.x + bb.x);
    o4.y = f2bf((v.y - mean) * rstd * gg.y + bb.y);
    o4.z = f2bf((v.z - mean) * rstd * gg.z + bb.z);
    o4.w = f2bf((v.w - mean) * rstd * gg.w + bb.w);
    *(ushort4*)(out + (size_t)row * C_ + lane * 4) = o4;
}

// ---------------------------------------------------------------------------
// bf16 MFMA GEMM, m97 structure: 128x128 tile, BK=64, LDS staging via
// global_load_lds (16B), 4 waves (2x2), wave tile 64x64 (4x4 frags 16x16x32).
// EPI: 0 bias->bf16 | 1 bias+unshift-scatter+residual(fp32)->fp32
// ---------------------------------------------------------------------------
template<int EPI>
__global__ __launch_bounds__(256) void mgemm(const unsigned short* __restrict__ A,
                                             const unsigned short* __restrict__ Bw,
                                             const float* __restrict__ bias,
                                             void* __restrict__ Cout,
                                             const float* __restrict__ resid,
                                             int M, int N, int K) {
    __shared__ unsigned short As[128 * 64];
    __shared__ unsigned short Bs[128 * 64];

    const int t    = threadIdx.x;
    const int wave = t >> 6, lane = t & 63;
    const int fr   = lane & 15, h = lane >> 4;
    const int wr   = wave >> 1, wc = wave & 1;
    const int m0   = blockIdx.y * 128;
    const int n0   = blockIdx.x * 128;
    const int moff = wr * 64, noff = wc * 64;

    const unsigned short* Ab = A  + (size_t)m0 * K;
    const unsigned short* Bb = Bw + (size_t)n0 * K;
    const int srow = t >> 3;            // 0..31 (per issue +32)
    const int scol = (t & 7) * 8;       // 0,8,...,56

    f32x4 acc[4][4] = {};

    for (int kt = 0; kt < K; kt += 64) {
#pragma unroll
        for (int i = 0; i < 4; ++i) {
            gload16(Ab + (size_t)(i * 32 + srow) * K + kt + scol,
                    &As[(i * 256 + wave * 64) * 8]);
            gload16(Bb + (size_t)(i * 32 + srow) * K + kt + scol,
                    &Bs[(i * 256 + wave * 64) * 8]);
        }
        __syncthreads();
#pragma unroll
        for (int ks = 0; ks < 2; ++ks) {
            bf16x8 a[4], b[4];
#pragma unroll
            for (int mi = 0; mi < 4; ++mi)
                a[mi] = *(const bf16x8*)&As[(moff + mi * 16 + fr) * 64 + ks * 32 + h * 8];
#pragma unroll
            for (int nj = 0; nj < 4; ++nj)
                b[nj] = *(const bf16x8*)&Bs[(noff + nj * 16 + fr) * 64 + ks * 32 + h * 8];
#pragma unroll
            for (int mi = 0; mi < 4; ++mi)
#pragma unroll
                for (int nj = 0; nj < 4; ++nj)
                    acc[mi][nj] = __builtin_amdgcn_mfma_f32_16x16x32_bf16(
                        a[mi], b[nj], acc[mi][nj], 0, 0, 0);
        }
        __syncthreads();
    }

    float bv[4];
#pragma unroll
    for (int nj = 0; nj < 4; ++nj) bv[nj] = bias[n0 + noff + nj * 16 + fr];

#pragma unroll
    for (int mi = 0; mi < 4; ++mi) {
#pragma unroll
        for (int nj = 0; nj < 4; ++nj) {
            const int col = n0 + noff + nj * 16 + fr;
#pragma unroll
            for (int j = 0; j < 4; ++j) {
                const int row = m0 + moff + mi * 16 + h * 4 + j;
                float v = acc[mi][nj][j] + bv[nj];
                if (EPI == 0) {
                    ((unsigned short*)Cout)[(size_t)row * N + col] = f2bf(v);
                } else { // EPI == 1
                    const int bimg = row >> 14;
                    const int rem  = row & 16383;
                    const int win  = rem >> 6;
                    const int tok  = rem & 63;
                    const int hp = (win >> 4) * 8 + (tok >> 3);
                    const int wp = (win & 15) * 8 + (tok & 7);
                    const int ho = (hp + SS_) & (H_ - 1);
                    const int wo = (wp + SS_) & (W_ - 1);
                    const size_t dst = ((size_t)(bimg << 14) + ho * W_ + wo) * C_ + col;
                    ((float*)Cout)[dst] = v + resid[dst];
                }
            }
        }
    }
}

// ---------------------------------------------------------------------------
// Fused MLP: out += gelu(LN2out @ W1^T + b1) @ W2^T + b2   (in-place residual)
// Block = 64 rows, 4 waves. A-tile staged in LDS (swizzled source). 16 chunks
// of 64 FC1-cols: phase A per-wave G chunk (rows-split) + gelu -> ping-pong
// G_lds; phase B accumulates O += G @ W2chunk^T. One barrier per chunk.
// ---------------------------------------------------------------------------
__global__ __launch_bounds__(256) void mlp_kernel(
    const unsigned short* __restrict__ A,   // [M][256] bf16 (ln2 out)
    const unsigned short* __restrict__ W1,  // [1024][256] bf16
    const float* __restrict__ b1,
    const unsigned short* __restrict__ W2,  // [256][1024] bf16
    const float* __restrict__ b2,
    float* __restrict__ out) {              // [M][256] fp32, in-place +=
    __shared__ unsigned short A_lds[64 * 256];
    __shared__ unsigned short G_lds[2][64 * 72];

    const int t = threadIdx.x;
    const int w = t >> 6, lane = t & 63;
    const int fr = lane & 15, h = lane >> 4;
    const int m0 = blockIdx.x * 64;

    // stage A: 64 rows x 512B, XOR-swizzled global source (lds dest linear)
#pragma unroll
    for (int i = 0; i < 8; ++i) {
        const int d    = i * 4096 + t * 16;            // dest byte offset
        const int row  = d >> 9;
        const int colb = (d & 511) ^ ((row & 7) << 4); // swizzled source col
        gload16(A + (size_t)(m0 + row) * 256 + (colb >> 1),
                (unsigned short*)((char*)A_lds + i * 4096 + w * 1024));
    }
    __syncthreads();

    f32x4 oacc[4][4] = {};

    const int   arow   = w * 16 + fr;                  // phase-A fragment row
    const char* a_base = (const char*)A_lds + arow * 512;
    const int   aswz   = (arow & 7) << 4;

    for (int c = 0; c < 16; ++c) {
        const int c0 = c * 64;
        unsigned short* Gb = G_lds[c & 1];

        // ---- phase A: G rows [w*16, w*16+16) x 64 chunk-cols
        bf16x8 aw[8];
#pragma unroll
        for (int ks = 0; ks < 8; ++ks) {
            const int kb = (ks * 32 + h * 8) * 2;
            aw[ks] = *(const bf16x8*)(a_base + (kb ^ aswz));
        }
        f32x4 st[4] = {};
#pragma unroll
        for (int nj = 0; nj < 4; ++nj) {
            const unsigned short* wp = W1 + (size_t)(c0 + nj * 16 + fr) * 256 + h * 8;
#pragma unroll
            for (int ks = 0; ks < 8; ++ks)
                st[nj] = __builtin_amdgcn_mfma_f32_16x16x32_bf16(
                    aw[ks], *(const bf16x8*)(wp + ks * 32), st[nj], 0, 0, 0);
        }
#pragma unroll
        for (int nj = 0; nj < 4; ++nj) {
            const float bb = b1[c0 + nj * 16 + fr];
#pragma unroll
            for (int j = 0; j < 4; ++j) {
                const float g = fast_gelu(st[nj][j] + bb);
                Gb[(w * 16 + h * 4 + j) * 72 + nj * 16 + fr] = f2bf(g);
            }
        }
        __syncthreads();

        // ---- phase B: oacc += G(64x64) @ W2chunk^T(64x64 per wave)
        bf16x8 pa[4][2], vb[4][2];
#pragma unroll
        for (int mi = 0; mi < 4; ++mi)
#pragma unroll
            for (int ks = 0; ks < 2; ++ks)
                pa[mi][ks] = *(const bf16x8*)&Gb[(mi * 16 + fr) * 72 + ks * 32 + h * 8];
#pragma unroll
        for (int nj = 0; nj < 4; ++nj)
#pragma unroll
            for (int ks = 0; ks < 2; ++ks)
                vb[nj][ks] = *(const bf16x8*)&W2[(size_t)(w * 64 + nj * 16 + fr) * 1024
                                                 + c0 + ks * 32 + h * 8];
#pragma unroll
        for (int mi = 0; mi < 4; ++mi)
#pragma unroll
            for (int nj = 0; nj < 4; ++nj)
#pragma unroll
                for (int ks = 0; ks < 2; ++ks)
                    oacc[mi][nj] = __builtin_amdgcn_mfma_f32_16x16x32_bf16(
                        pa[mi][ks], vb[nj][ks], oacc[mi][nj], 0, 0, 0);
        // no second barrier: ping-pong G buffers make write(c+1) ⟂ read(c)
    }

    // epilogue: out += oacc + b2
    float bv2[4];
#pragma unroll
    for (int nj = 0; nj < 4; ++nj) bv2[nj] = b2[w * 64 + nj * 16 + fr];
#pragma unroll
    for (int mi = 0; mi < 4; ++mi)
#pragma unroll
        for (int nj = 0; nj < 4; ++nj) {
            const int col = w * 64 + nj * 16 + fr;
#pragma unroll
            for (int j = 0; j < 4; ++j) {
                const size_t idx = (size_t)(m0 + mi * 16 + h * 4 + j) * 256 + col;
                out[idx] += oacc[mi][nj][j] + bv2[nj];
            }
        }
}

// ---------------------------------------------------------------------------
// MFMA windowed attention (unchanged from round 3 — passing).
// ---------------------------------------------------------------------------
__device__ __forceinline__ int grp_(int p) { return p < (H_ - WS_) ? 0 : (p < (H_ - SS_) ? 1 : 2); }

__global__ __launch_bounds__(256) void attn_kernel(const unsigned short* __restrict__ qkv,
                                                   const float* __restrict__ rpb,
                                                   unsigned short* __restrict__ out) {
    __shared__ unsigned short P [4][64 * 72];
    __shared__ unsigned short Vt[4][32 * 72];
    __shared__ float rpb_s[232];

    const int t    = threadIdx.x;
    const int wid  = t >> 6, lane = t & 63;
    const int head = blockIdx.x & 7;
    const int win  = (blockIdx.x >> 3) * 4 + wid;
    const int fr   = lane & 15, h = lane >> 4;

    if (t < 225) rpb_s[t] = rpb[t * 8 + head];
    __syncthreads();

    const size_t qbase = (size_t)win * 64 * 768 + head * HD_;

    bf16x8 ak[4], bq[4];
#pragma unroll
    for (int ki = 0; ki < 4; ++ki)
        ak[ki] = *(const bf16x8*)&qkv[qbase + (size_t)(ki * 16 + fr) * 768 + 256 + h * 8];
#pragma unroll
    for (int qj = 0; qj < 4; ++qj)
        bq[qj] = *(const bf16x8*)&qkv[qbase + (size_t)(qj * 16 + fr) * 768 + h * 8];

    {
        const unsigned short* vrow = &qkv[qbase + (size_t)lane * 768 + 512];
#pragma unroll
        for (int dv = 0; dv < 32; dv += 8) {
            bf16x8 v8 = *(const bf16x8*)&vrow[dv];
#pragma unroll
            for (int j = 0; j < 8; ++j)
                Vt[wid][(dv + j) * 72 + lane] = ((unsigned short*)&v8)[j];
        }
    }

    f32x4 st[4][4] = {};
#pragma unroll
    for (int ki = 0; ki < 4; ++ki)
#pragma unroll
        for (int qj = 0; qj < 4; ++qj)
            st[ki][qj] = __builtin_amdgcn_mfma_f32_16x16x32_bf16(ak[ki], bq[qj], st[ki][qj], 0, 0, 0);

    const int wim = win & 255;
    const int whb = (wim >> 4) * 8, wwb = (wim & 15) * 8;
    const float qscale = 0.17677669529663687f;

#pragma unroll
    for (int qj = 0; qj < 4; ++qj) {
        const int q  = qj * 16 + fr;
        const int yq = q >> 3, xq = q & 7;
        const int gq = grp_(whb + yq) * 3 + grp_(wwb + xq);
        float s[16];
#pragma unroll
        for (int ki = 0; ki < 4; ++ki)
#pragma unroll
            for (int r = 0; r < 4; ++r) {
                const int k  = ki * 16 + h * 4 + r;
                const int yk = k >> 3, xk = k & 7;
                const int gk = grp_(whb + yk) * 3 + grp_(wwb + xk);
                float v = fmaf(st[ki][qj][r], qscale,
                               rpb_s[(yq - yk + 7) * 15 + (xq - xk + 7)]);
                if (gk != gq) v -= 100.0f;
                s[ki * 4 + r] = v;
            }
        float m = s[0];
#pragma unroll
        for (int i = 1; i < 16; ++i) m = fmaxf(m, s[i]);
        m = fmaxf(m, __shfl_xor(m, 16, 64));
        m = fmaxf(m, __shfl_xor(m, 32, 64));
        float sum = 0.0f;
#pragma unroll
        for (int i = 0; i < 16; ++i) { s[i] = __expf(s[i] - m); sum += s[i]; }
        sum += __shfl_xor(sum, 16, 64);
        sum += __shfl_xor(sum, 32, 64);
        const float rinv = __builtin_amdgcn_rcpf(sum);
#pragma unroll
        for (int ki = 0; ki < 4; ++ki)
#pragma unroll
            for (int rp = 0; rp < 4; rp += 2) {
                const unsigned int lo = f2bf(s[ki * 4 + rp]     * rinv);
                const unsigned int hi = f2bf(s[ki * 4 + rp + 1] * rinv);
                *(unsigned int*)&P[wid][q * 72 + ki * 16 + h * 4 + rp] = lo | (hi << 16);
            }
    }

    f32x4 oacc[4][2] = {};
#pragma unroll
    for (int ks = 0; ks < 2; ++ks) {
        bf16x8 pa[4], vb[2];
#pragma unroll
        for (int qi = 0; qi < 4; ++qi)
            pa[qi] = *(const bf16x8*)&P[wid][(qi * 16 + fr) * 72 + ks * 32 + h * 8];
#pragma unroll
        for (int nj = 0; nj < 2; ++nj)
            vb[nj] = *(const bf16x8*)&Vt[wid][(nj * 16 + fr) * 72 + ks * 32 + h * 8];
#pragma unroll
        for (int qi = 0; qi < 4; ++qi)
#pragma unroll
            for (int nj = 0; nj < 2; ++nj)
                oacc[qi][nj] = __builtin_amdgcn_mfma_f32_16x16x32_bf16(pa[qi], vb[nj], oacc[qi][nj], 0, 0, 0);
    }

#pragma unroll
    for (int qi = 0; qi < 4; ++qi)
#pragma unroll
        for (int nj = 0; nj < 2; ++nj)
#pragma unroll
            for (int r = 0; r < 4; ++r) {
                const int q = qi * 16 + h * 4 + r;
                const int d = nj * 16 + fr;
                out[((size_t)win * 64 + q) * C_ + head * HD_ + d] = f2bf(oacc[qi][nj][r]);
            }
}

// ---------------------------------------------------------------------------
extern "C" void kernel_launch(void* const* d_in, const int* in_sizes, int n_in,
                              void* d_out, int out_size, void* d_ws, size_t ws_size,
                              hipStream_t stream) {
    const float* x      = (const float*)d_in[0];
    const float* n1g    = (const float*)d_in[1];
    const float* n1b    = (const float*)d_in[2];
    const float* qkv_w  = (const float*)d_in[3];
    const float* qkv_b  = (const float*)d_in[4];
    const float* rpb    = (const float*)d_in[5];
    const float* proj_w = (const float*)d_in[6];
    const float* proj_b = (const float*)d_in[7];
    const float* n2g    = (const float*)d_in[8];
    const float* n2b    = (const float*)d_in[9];
    const float* fc1_w  = (const float*)d_in[10];
    const float* fc1_b  = (const float*)d_in[11];
    const float* fc2_w  = (const float*)d_in[12];
    const float* fc2_b  = (const float*)d_in[13];
    float* out = (float*)d_out;

    // workspace (bf16 elements)
    unsigned short* wq  = (unsigned short*)d_ws;         // weights bf16
    unsigned short* rA  = wq + (1u << 20);               // 64 MB region
    unsigned short* rB  = rA + 33554432u;                // 256 MB region (qkv)

    unsigned short* qkv_wb  = wq;
    unsigned short* proj_wb = wq + 196608;
    unsigned short* fc1_wb  = wq + 262144;
    unsigned short* fc2_wb  = wq + 524288;

    cvt4<<<192, 256, 0, stream>>>(qkv_w,  qkv_wb,  196608);
    cvt4<<<64,  256, 0, stream>>>(proj_w, proj_wb, 65536);
    cvt4<<<256, 256, 0, stream>>>(fc1_w,  fc1_wb,  262144);
    cvt4<<<256, 256, 0, stream>>>(fc2_w,  fc2_wb,  262144);

    // 1. LN1 + cyclic shift + window partition  (x -> rA bf16)
    ln_kernel<1><<<MROWS / 4, 256, 0, stream>>>(x, n1g, n1b, rA);
    // 2. QKV projection (rA -> rB bf16)
    mgemm<0><<<dim3(768 / 128, MROWS / 128), 256, 0, stream>>>(
        rA, qkv_wb, qkv_b, rB, nullptr, MROWS, 768, 256);
    // 3. windowed attention (rB -> rA bf16)
    attn_kernel<<<(2048 / 4) * NH_, 256, 0, stream>>>(rB, rpb, rA);
    // 4. proj + window-reverse/unshift scatter + residual -> d_out fp32
    mgemm<1><<<dim3(256 / 128, MROWS / 128), 256, 0, stream>>>(
        rA, proj_wb, proj_b, out, x, MROWS, 256, 256);
    // 5. LN2 (out -> rA bf16)
    ln_kernel<0><<<MROWS / 4, 256, 0, stream>>>(out, n2g, n2b, rA);
    // 6+7. fused MLP: out += gelu(rA @ W1^T + b1) @ W2^T + b2
    mlp_kernel<<<MROWS / 64, 256, 0, stream>>>(rA, fc1_wb, fc1_b, fc2_wb, fc2_b, out);
}

// Round 5
// 739.650 us; speedup vs baseline: 1.3013x; 1.3013x over previous
//
#include <hip/hip_runtime.h>
#include <math.h>

// Problem constants
#define B_   8
#define H_   128
#define W_   128
#define C_   256
#define WS_  8
#define SS_  4
#define NH_  8
#define HD_  32
#define MROWS 131072   // B * H * W tokens

typedef short bf16x8 __attribute__((ext_vector_type(8)));
typedef float f32x4  __attribute__((ext_vector_type(4)));

__device__ __forceinline__ unsigned short f2bf(float f) {
    unsigned int u = __float_as_uint(f);
    u += 0x7fffu + ((u >> 16) & 1u);          // round-to-nearest-even
    return (unsigned short)(u >> 16);
}

// async global->LDS, 16 bytes per lane; lds dest = wave-uniform base + lane*16
__device__ __forceinline__ void gload16(const unsigned short* g, unsigned short* l) {
    __builtin_amdgcn_global_load_lds(
        (const __attribute__((address_space(1))) unsigned int*)(const void*)g,
        (__attribute__((address_space(3))) unsigned int*)(void*)l, 16, 0, 0);
}

// fast exact-GELU: erf via Abramowitz-Stegun 7.1.26 (|err| <= 1.5e-7)
__device__ __forceinline__ float fast_gelu(float v) {
    const float x  = v * 0.70710678118654752f;
    const float ax = fabsf(x);
    const float t  = __builtin_amdgcn_rcpf(fmaf(0.3275911f, ax, 1.0f));
    float p = fmaf(1.061405429f, t, -1.453152027f);
    p = fmaf(p, t, 1.421413741f);
    p = fmaf(p, t, -0.284496736f);
    p = fmaf(p, t, 0.254829592f);
    p *= t;
    const float e  = __expf(-ax * ax);
    const float er = copysignf(1.0f - p * e, x);
    return 0.5f * v * (1.0f + er);
}

// ---------------------------------------------------------------------------
// fp32 -> bf16 weight conversion
// ---------------------------------------------------------------------------
__global__ __launch_bounds__(256) void cvt4(const float* __restrict__ s,
                                            unsigned short* __restrict__ d, int n) {
    const int i = (blockIdx.x * 256 + threadIdx.x) * 4;
    if (i >= n) return;
    const float4 v = *(const float4*)(s + i);
    ushort4 o;
    o.x = f2bf(v.x); o.y = f2bf(v.y); o.z = f2bf(v.z); o.w = f2bf(v.w);
    *(ushort4*)(d + i) = o;
}

// ---------------------------------------------------------------------------
// LayerNorm: one wave per token, 4 channels/lane. fp32 in -> bf16 out.
// SHIFT=1: dest row is (shifted frame, window-partition) layout.
// ---------------------------------------------------------------------------
template<int SHIFT>
__global__ __launch_bounds__(256) void ln_kernel(const float* __restrict__ in,
                                                 const float* __restrict__ g,
                                                 const float* __restrict__ b,
                                                 unsigned short* __restrict__ out) {
    const int wid  = threadIdx.x >> 6;
    const int lane = threadIdx.x & 63;
    const int row  = blockIdx.x * 4 + wid;

    int src;
    if (SHIFT) {
        const int bimg = row >> 14;
        const int rem  = row & 16383;
        const int win  = rem >> 6;
        const int tok  = rem & 63;
        const int hp = (win >> 4) * 8 + (tok >> 3);
        const int wp = (win & 15) * 8 + (tok & 7);
        const int ho = (hp + SS_) & (H_ - 1);
        const int wo = (wp + SS_) & (W_ - 1);
        src = (bimg << 14) + ho * W_ + wo;
    } else {
        src = row;
    }

    const float4 v = ((const float4*)(in + (size_t)src * C_))[lane];
    float s  = v.x + v.y + v.z + v.w;
    float ss = v.x*v.x + v.y*v.y + v.z*v.z + v.w*v.w;
#pragma unroll
    for (int o = 1; o < 64; o <<= 1) {
        s  += __shfl_xor(s,  o, 64);
        ss += __shfl_xor(ss, o, 64);
    }
    const float mean = s * (1.0f / C_);
    const float var  = ss * (1.0f / C_) - mean * mean;
    const float rstd = rsqrtf(var + 1e-5f);

    const float4 gg = ((const float4*)g)[lane];
    const float4 bb = ((const float4*)b)[lane];
    ushort4 o4;
    o4.x = f2bf((v.x - mean) * rstd * gg.x + bb.x);
    o4.y = f2bf((v.y - mean) * rstd * gg.y + bb.y);
    o4.z = f2bf((v.z - mean) * rstd * gg.z + bb.z);
    o4.w = f2bf((v.w - mean) * rstd * gg.w + bb.w);
    *(ushort4*)(out + (size_t)row * C_ + lane * 4) = o4;
}

// ---------------------------------------------------------------------------
// K=256 GEMM with A-in-registers and an n-tile loop.
// Block = 128 rows, 4 waves (each owns 32 rows); A wave-tile in 16 bf16x8
// regs. Per 128-col n-tile: stage W (128x256 bf16, 64KB) into LDS via
// global_load_lds with XOR-pre-swizzled SOURCE (linear dest), then each wave
// does 128 MFMAs (8 nj x 2 mi x 8 ks). mfma(w,a) -> D[reg=n][lane&15=m]:
// lane holds 4 consecutive n -> packed stores.
// EPI: 0 bias->bf16 | 1 bias+unshift-scatter+residual->fp32 | 2 bias+GELU->bf16
// ---------------------------------------------------------------------------
template<int EPI, int N>
__global__ __launch_bounds__(256) void gemm_nloop(const unsigned short* __restrict__ A,
                                                  const unsigned short* __restrict__ W,
                                                  const float* __restrict__ bias,
                                                  void* __restrict__ Cout,
                                                  const float* __restrict__ resid) {
    __shared__ unsigned short W_lds[128 * 256];

    const int t    = threadIdx.x;
    const int wave = t >> 6, lane = t & 63;
    const int fr   = lane & 15, h = lane >> 4;
    const int m0   = blockIdx.x * 128;

    // A fragments: wave owns rows [wave*32, wave*32+32), full K=256
    bf16x8 aw[2][8];
    const unsigned short* Abase = A + (size_t)(m0 + wave * 32 + fr) * 256 + h * 8;
#pragma unroll
    for (int mi = 0; mi < 2; ++mi)
#pragma unroll
        for (int ks = 0; ks < 8; ++ks)
            aw[mi][ks] = *(const bf16x8*)(Abase + mi * 16 * 256 + ks * 32);

    for (int nt = 0; nt < N / 128; ++nt) {
        // stage W tile [128][256]: linear LDS dest, swizzled global source
        const unsigned short* Wt = W + (size_t)nt * 128 * 256;
#pragma unroll
        for (int r = 0; r < 16; ++r) {
            const int d    = r * 4096 + t * 16;            // dest byte offset
            const int row  = d >> 9;
            const int colb = (d & 511) ^ ((row & 7) << 4);
            gload16(Wt + (size_t)row * 256 + (colb >> 1),
                    (unsigned short*)((char*)W_lds + r * 4096 + wave * 1024));
        }
        __syncthreads();

        f32x4 acc[2][8] = {};
#pragma unroll
        for (int nj = 0; nj < 8; ++nj) {
            const int   wrow = nj * 16 + fr;
            const char* wb   = (const char*)W_lds + wrow * 512;
            const int   swz  = (fr & 7) << 4;
            bf16x8 wf[8];
#pragma unroll
            for (int ks = 0; ks < 8; ++ks)
                wf[ks] = *(const bf16x8*)(wb + ((ks * 64 + h * 16) ^ swz));
#pragma unroll
            for (int ks = 0; ks < 8; ++ks) {
                acc[0][nj] = __builtin_amdgcn_mfma_f32_16x16x32_bf16(wf[ks], aw[0][ks], acc[0][nj], 0, 0, 0);
                acc[1][nj] = __builtin_amdgcn_mfma_f32_16x16x32_bf16(wf[ks], aw[1][ks], acc[1][nj], 0, 0, 0);
            }
        }

        // epilogue: m = m0+wave*32+mi*16+fr ; n = nt*128+nj*16+h*4 (+j)
#pragma unroll
        for (int mi = 0; mi < 2; ++mi) {
            const int m = m0 + wave * 32 + mi * 16 + fr;
#pragma unroll
            for (int nj = 0; nj < 8; ++nj) {
                const int n = nt * 128 + nj * 16 + h * 4;
                const float4 bb = *(const float4*)&bias[n];
                float v0 = acc[mi][nj][0] + bb.x;
                float v1 = acc[mi][nj][1] + bb.y;
                float v2 = acc[mi][nj][2] + bb.z;
                float v3 = acc[mi][nj][3] + bb.w;
                if (EPI == 2) {
                    v0 = fast_gelu(v0); v1 = fast_gelu(v1);
                    v2 = fast_gelu(v2); v3 = fast_gelu(v3);
                }
                if (EPI == 0 || EPI == 2) {
                    uint2 pk;
                    pk.x = (unsigned int)f2bf(v0) | ((unsigned int)f2bf(v1) << 16);
                    pk.y = (unsigned int)f2bf(v2) | ((unsigned int)f2bf(v3) << 16);
                    *(uint2*)&((unsigned short*)Cout)[(size_t)m * N + n] = pk;
                } else { // EPI == 1: window-reverse + unshift scatter + residual
                    const int bimg = m >> 14;
                    const int rem  = m & 16383;
                    const int win  = rem >> 6;
                    const int tok  = rem & 63;
                    const int hp = (win >> 4) * 8 + (tok >> 3);
                    const int wp = (win & 15) * 8 + (tok & 7);
                    const int ho = (hp + SS_) & (H_ - 1);
                    const int wo = (wp + SS_) & (W_ - 1);
                    const size_t dst = ((size_t)(bimg << 14) + ho * W_ + wo) * 256 + n;
                    const float4 r4 = *(const float4*)&resid[dst];
                    float4 o;
                    o.x = v0 + r4.x; o.y = v1 + r4.y; o.z = v2 + r4.z; o.w = v3 + r4.w;
                    *(float4*)&((float*)Cout)[dst] = o;
                }
            }
        }
        __syncthreads();
    }
}

// ---------------------------------------------------------------------------
// FC2 GEMM: out[M,256] += A[M,1024] @ W2[256,1024]^T + b2. BM=128, BN=256,
// BK=64 LDS staging (proven m97-style loop), 4 waves (2x2), wave 64x128.
// Swapped mfma -> packed float4 residual RMW epilogue.
// ---------------------------------------------------------------------------
__global__ __launch_bounds__(256) void fc2_gemm(const unsigned short* __restrict__ A,
                                                const unsigned short* __restrict__ W2,
                                                const float* __restrict__ b2,
                                                float* __restrict__ out) {
    __shared__ unsigned short As[128 * 64];
    __shared__ unsigned short Bs[256 * 64];

    const int t    = threadIdx.x;
    const int wave = t >> 6, lane = t & 63;
    const int fr   = lane & 15, h = lane >> 4;
    const int wr   = wave >> 1, wc = wave & 1;
    const int m0   = blockIdx.x * 128;

    const int srow = t >> 3;            // 0..31 per issue round
    const int scol = (t & 7) * 8;

    f32x4 acc[4][8] = {};

    for (int kt = 0; kt < 1024; kt += 64) {
#pragma unroll
        for (int i = 0; i < 4; ++i)
            gload16(A + (size_t)(m0 + i * 32 + srow) * 1024 + kt + scol,
                    &As[(i * 256 + wave * 64) * 8]);
#pragma unroll
        for (int i = 0; i < 8; ++i)
            gload16(W2 + (size_t)(i * 32 + srow) * 1024 + kt + scol,
                    &Bs[(i * 256 + wave * 64) * 8]);
        __syncthreads();
#pragma unroll
        for (int ks = 0; ks < 2; ++ks) {
            bf16x8 a[4], b[8];
#pragma unroll
            for (int mi = 0; mi < 4; ++mi)
                a[mi] = *(const bf16x8*)&As[(wr * 64 + mi * 16 + fr) * 64 + ks * 32 + h * 8];
#pragma unroll
            for (int nj = 0; nj < 8; ++nj)
                b[nj] = *(const bf16x8*)&Bs[(wc * 128 + nj * 16 + fr) * 64 + ks * 32 + h * 8];
#pragma unroll
            for (int mi = 0; mi < 4; ++mi)
#pragma unroll
                for (int nj = 0; nj < 8; ++nj)
                    acc[mi][nj] = __builtin_amdgcn_mfma_f32_16x16x32_bf16(
                        b[nj], a[mi], acc[mi][nj], 0, 0, 0);
        }
        __syncthreads();
    }

    // epilogue: m = m0+wr*64+mi*16+fr ; n = wc*128+nj*16+h*4 (+j)
#pragma unroll
    for (int mi = 0; mi < 4; ++mi) {
        const int m = m0 + wr * 64 + mi * 16 + fr;
#pragma unroll
        for (int nj = 0; nj < 8; ++nj) {
            const int n = wc * 128 + nj * 16 + h * 4;
            const float4 bb = *(const float4*)&b2[n];
            const size_t idx = (size_t)m * 256 + n;
            const float4 r4 = *(const float4*)&out[idx];
            float4 o;
            o.x = acc[mi][nj][0] + bb.x + r4.x;
            o.y = acc[mi][nj][1] + bb.y + r4.y;
            o.z = acc[mi][nj][2] + bb.z + r4.z;
            o.w = acc[mi][nj][3] + bb.w + r4.w;
            *(float4*)&out[idx] = o;
        }
    }
}

// ---------------------------------------------------------------------------
// MFMA windowed attention (unchanged — passing).
// ---------------------------------------------------------------------------
__device__ __forceinline__ int grp_(int p) { return p < (H_ - WS_) ? 0 : (p < (H_ - SS_) ? 1 : 2); }

__global__ __launch_bounds__(256) void attn_kernel(const unsigned short* __restrict__ qkv,
                                                   const float* __restrict__ rpb,
                                                   unsigned short* __restrict__ out) {
    __shared__ unsigned short P [4][64 * 72];
    __shared__ unsigned short Vt[4][32 * 72];
    __shared__ float rpb_s[232];

    const int t    = threadIdx.x;
    const int wid  = t >> 6, lane = t & 63;
    const int head = blockIdx.x & 7;
    const int win  = (blockIdx.x >> 3) * 4 + wid;
    const int fr   = lane & 15, h = lane >> 4;

    if (t < 225) rpb_s[t] = rpb[t * 8 + head];
    __syncthreads();

    const size_t qbase = (size_t)win * 64 * 768 + head * HD_;

    bf16x8 ak[4], bq[4];
#pragma unroll
    for (int ki = 0; ki < 4; ++ki)
        ak[ki] = *(const bf16x8*)&qkv[qbase + (size_t)(ki * 16 + fr) * 768 + 256 + h * 8];
#pragma unroll
    for (int qj = 0; qj < 4; ++qj)
        bq[qj] = *(const bf16x8*)&qkv[qbase + (size_t)(qj * 16 + fr) * 768 + h * 8];

    {
        const unsigned short* vrow = &qkv[qbase + (size_t)lane * 768 + 512];
#pragma unroll
        for (int dv = 0; dv < 32; dv += 8) {
            bf16x8 v8 = *(const bf16x8*)&vrow[dv];
#pragma unroll
            for (int j = 0; j < 8; ++j)
                Vt[wid][(dv + j) * 72 + lane] = ((unsigned short*)&v8)[j];
        }
    }

    f32x4 st[4][4] = {};
#pragma unroll
    for (int ki = 0; ki < 4; ++ki)
#pragma unroll
        for (int qj = 0; qj < 4; ++qj)
            st[ki][qj] = __builtin_amdgcn_mfma_f32_16x16x32_bf16(ak[ki], bq[qj], st[ki][qj], 0, 0, 0);

    const int wim = win & 255;
    const int whb = (wim >> 4) * 8, wwb = (wim & 15) * 8;
    const float qscale = 0.17677669529663687f;

#pragma unroll
    for (int qj = 0; qj < 4; ++qj) {
        const int q  = qj * 16 + fr;
        const int yq = q >> 3, xq = q & 7;
        const int gq = grp_(whb + yq) * 3 + grp_(wwb + xq);
        float s[16];
#pragma unroll
        for (int ki = 0; ki < 4; ++ki)
#pragma unroll
            for (int r = 0; r < 4; ++r) {
                const int k  = ki * 16 + h * 4 + r;
                const int yk = k >> 3, xk = k & 7;
                const int gk = grp_(whb + yk) * 3 + grp_(wwb + xk);
                float v = fmaf(st[ki][qj][r], qscale,
                               rpb_s[(yq - yk + 7) * 15 + (xq - xk + 7)]);
                if (gk != gq) v -= 100.0f;
                s[ki * 4 + r] = v;
            }
        float m = s[0];
#pragma unroll
        for (int i = 1; i < 16; ++i) m = fmaxf(m, s[i]);
        m = fmaxf(m, __shfl_xor(m, 16, 64));
        m = fmaxf(m, __shfl_xor(m, 32, 64));
        float sum = 0.0f;
#pragma unroll
        for (int i = 0; i < 16; ++i) { s[i] = __expf(s[i] - m); sum += s[i]; }
        sum += __shfl_xor(sum, 16, 64);
        sum += __shfl_xor(sum, 32, 64);
        const float rinv = __builtin_amdgcn_rcpf(sum);
#pragma unroll
        for (int ki = 0; ki < 4; ++ki)
#pragma unroll
            for (int rp = 0; rp < 4; rp += 2) {
                const unsigned int lo = f2bf(s[ki * 4 + rp]     * rinv);
                const unsigned int hi = f2bf(s[ki * 4 + rp + 1] * rinv);
                *(unsigned int*)&P[wid][q * 72 + ki * 16 + h * 4 + rp] = lo | (hi << 16);
            }
    }

    f32x4 oacc[4][2] = {};
#pragma unroll
    for (int ks = 0; ks < 2; ++ks) {
        bf16x8 pa[4], vb[2];
#pragma unroll
        for (int qi = 0; qi < 4; ++qi)
            pa[qi] = *(const bf16x8*)&P[wid][(qi * 16 + fr) * 72 + ks * 32 + h * 8];
#pragma unroll
        for (int nj = 0; nj < 2; ++nj)
            vb[nj] = *(const bf16x8*)&Vt[wid][(nj * 16 + fr) * 72 + ks * 32 + h * 8];
#pragma unroll
        for (int qi = 0; qi < 4; ++qi)
#pragma unroll
            for (int nj = 0; nj < 2; ++nj)
                oacc[qi][nj] = __builtin_amdgcn_mfma_f32_16x16x32_bf16(pa[qi], vb[nj], oacc[qi][nj], 0, 0, 0);
    }

#pragma unroll
    for (int qi = 0; qi < 4; ++qi)
#pragma unroll
        for (int nj = 0; nj < 2; ++nj)
#pragma unroll
            for (int r = 0; r < 4; ++r) {
                const int q = qi * 16 + h * 4 + r;
                const int d = nj * 16 + fr;
                out[((size_t)win * 64 + q) * C_ + head * HD_ + d] = f2bf(oacc[qi][nj][r]);
            }
}

// ---------------------------------------------------------------------------
extern "C" void kernel_launch(void* const* d_in, const int* in_sizes, int n_in,
                              void* d_out, int out_size, void* d_ws, size_t ws_size,
                              hipStream_t stream) {
    const float* x      = (const float*)d_in[0];
    const float* n1g    = (const float*)d_in[1];
    const float* n1b    = (const float*)d_in[2];
    const float* qkv_w  = (const float*)d_in[3];
    const float* qkv_b  = (const float*)d_in[4];
    const float* rpb    = (const float*)d_in[5];
    const float* proj_w = (const float*)d_in[6];
    const float* proj_b = (const float*)d_in[7];
    const float* n2g    = (const float*)d_in[8];
    const float* n2b    = (const float*)d_in[9];
    const float* fc1_w  = (const float*)d_in[10];
    const float* fc1_b  = (const float*)d_in[11];
    const float* fc2_w  = (const float*)d_in[12];
    const float* fc2_b  = (const float*)d_in[13];
    float* out = (float*)d_out;

    // workspace (bf16 elements)
    unsigned short* wq  = (unsigned short*)d_ws;         // weights bf16
    unsigned short* rA  = wq + (1u << 20);               // 64 MB region
    unsigned short* rB  = rA + 33554432u;                // 256 MB region

    unsigned short* qkv_wb  = wq;
    unsigned short* proj_wb = wq + 196608;
    unsigned short* fc1_wb  = wq + 262144;
    unsigned short* fc2_wb  = wq + 524288;

    cvt4<<<192, 256, 0, stream>>>(qkv_w,  qkv_wb,  196608);
    cvt4<<<64,  256, 0, stream>>>(proj_w, proj_wb, 65536);
    cvt4<<<256, 256, 0, stream>>>(fc1_w,  fc1_wb,  262144);
    cvt4<<<256, 256, 0, stream>>>(fc2_w,  fc2_wb,  262144);

    // 1. LN1 + cyclic shift + window partition  (x -> rA bf16)
    ln_kernel<1><<<MROWS / 4, 256, 0, stream>>>(x, n1g, n1b, rA);
    // 2. QKV projection (rA -> rB bf16)
    gemm_nloop<0, 768><<<MROWS / 128, 256, 0, stream>>>(rA, qkv_wb, qkv_b, rB, nullptr);
    // 3. windowed attention (rB -> rA bf16)
    attn_kernel<<<(2048 / 4) * NH_, 256, 0, stream>>>(rB, rpb, rA);
    // 4. proj + window-reverse/unshift scatter + residual -> d_out fp32
    gemm_nloop<1, 256><<<MROWS / 128, 256, 0, stream>>>(rA, proj_wb, proj_b, out, x);
    // 5. LN2 (out -> rA bf16)
    ln_kernel<0><<<MROWS / 4, 256, 0, stream>>>(out, n2g, n2b, rA);
    // 6. FC1 + fast GELU (rA -> rB bf16)
    gemm_nloop<2, 1024><<<MROWS / 128, 256, 0, stream>>>(rA, fc1_wb, fc1_b, rB, nullptr);
    // 7. FC2 + residual (in-place on d_out fp32)
    fc2_gemm<<<MROWS / 128, 256, 0, stream>>>(rB, fc2_wb, fc2_b, out);
}

// Round 6
// 656.602 us; speedup vs baseline: 1.4659x; 1.1265x over previous
//
#include <hip/hip_runtime.h>
#include <math.h>

// Problem constants
#define B_   8
#define H_   128
#define W_   128
#define C_   256
#define WS_  8
#define SS_  4
#define NH_  8
#define HD_  32
#define MROWS 131072   // B * H * W tokens

typedef short bf16x8 __attribute__((ext_vector_type(8)));
typedef float f32x4  __attribute__((ext_vector_type(4)));

__device__ __forceinline__ unsigned short f2bf(float f) {
    unsigned int u = __float_as_uint(f);
    u += 0x7fffu + ((u >> 16) & 1u);          // round-to-nearest-even
    return (unsigned short)(u >> 16);
}

// async global->LDS, 16 bytes per lane; lds dest = wave-uniform base + lane*16
__device__ __forceinline__ void gload16(const unsigned short* g, unsigned short* l) {
    __builtin_amdgcn_global_load_lds(
        (const __attribute__((address_space(1))) unsigned int*)(const void*)g,
        (__attribute__((address_space(3))) unsigned int*)(void*)l, 16, 0, 0);
}

// fast exact-GELU: erf via Abramowitz-Stegun 7.1.26 (|err| <= 1.5e-7)
__device__ __forceinline__ float fast_gelu(float v) {
    const float x  = v * 0.70710678118654752f;
    const float ax = fabsf(x);
    const float t  = __builtin_amdgcn_rcpf(fmaf(0.3275911f, ax, 1.0f));
    float p = fmaf(1.061405429f, t, -1.453152027f);
    p = fmaf(p, t, 1.421413741f);
    p = fmaf(p, t, -0.284496736f);
    p = fmaf(p, t, 0.254829592f);
    p *= t;
    const float e  = __expf(-ax * ax);
    const float er = copysignf(1.0f - p * e, x);
    return 0.5f * v * (1.0f + er);
}

// ---------------------------------------------------------------------------
// fp32 -> bf16 weight conversion
// ---------------------------------------------------------------------------
__global__ __launch_bounds__(256) void cvt4(const float* __restrict__ s,
                                            unsigned short* __restrict__ d, int n) {
    const int i = (blockIdx.x * 256 + threadIdx.x) * 4;
    if (i >= n) return;
    const float4 v = *(const float4*)(s + i);
    ushort4 o;
    o.x = f2bf(v.x); o.y = f2bf(v.y); o.z = f2bf(v.z); o.w = f2bf(v.w);
    *(ushort4*)(d + i) = o;
}

// ---------------------------------------------------------------------------
// LayerNorm: one wave per token. fp32 in -> bf16 out. SHIFT=1: dest row is
// (shifted frame, window-partition) layout.
// ---------------------------------------------------------------------------
template<int SHIFT>
__global__ __launch_bounds__(256) void ln_kernel(const float* __restrict__ in,
                                                 const float* __restrict__ g,
                                                 const float* __restrict__ b,
                                                 unsigned short* __restrict__ out) {
    const int wid  = threadIdx.x >> 6;
    const int lane = threadIdx.x & 63;
    const int row  = blockIdx.x * 4 + wid;

    int src;
    if (SHIFT) {
        const int bimg = row >> 14;
        const int rem  = row & 16383;
        const int win  = rem >> 6;
        const int tok  = rem & 63;
        const int hp = (win >> 4) * 8 + (tok >> 3);
        const int wp = (win & 15) * 8 + (tok & 7);
        const int ho = (hp + SS_) & (H_ - 1);
        const int wo = (wp + SS_) & (W_ - 1);
        src = (bimg << 14) + ho * W_ + wo;
    } else {
        src = row;
    }

    const float4 v = ((const float4*)(in + (size_t)src * C_))[lane];
    float s  = v.x + v.y + v.z + v.w;
    float ss = v.x*v.x + v.y*v.y + v.z*v.z + v.w*v.w;
#pragma unroll
    for (int o = 1; o < 64; o <<= 1) {
        s  += __shfl_xor(s,  o, 64);
        ss += __shfl_xor(ss, o, 64);
    }
    const float mean = s * (1.0f / C_);
    const float var  = ss * (1.0f / C_) - mean * mean;
    const float rstd = rsqrtf(var + 1e-5f);

    const float4 gg = ((const float4*)g)[lane];
    const float4 bb = ((const float4*)b)[lane];
    ushort4 o4;
    o4.x = f2bf((v.x - mean) * rstd * gg.x + bb.x);
    o4.y = f2bf((v.y - mean) * rstd * gg.y + bb.y);
    o4.z = f2bf((v.z - mean) * rstd * gg.z + bb.z);
    o4.w = f2bf((v.w - mean) * rstd * gg.w + bb.w);
    *(ushort4*)(out + (size_t)row * C_ + lane * 4) = o4;
}

// ---------------------------------------------------------------------------
// K=256 GEMM, A-in-registers, 2-phase prefetch over 64-col n-tiles.
// Block = 128 rows, 4 waves (32 rows each). W tile (64x256, 32KB) double-
// buffered in LDS; stage(next) issued BEFORE compute(current); one barrier
// per tile. W staged via gload16 with XOR-pre-swizzled source.
// EPI: 0 bias->bf16 | 2 bias+GELU->bf16
// ---------------------------------------------------------------------------
template<int EPI, int N>
__global__ __launch_bounds__(256, 2) void gemm_nloop(const unsigned short* __restrict__ A,
                                                     const unsigned short* __restrict__ W,
                                                     const float* __restrict__ bias,
                                                     unsigned short* __restrict__ Cout) {
    __shared__ unsigned short W_lds[2][64 * 256];

    const int t    = threadIdx.x;
    const int wave = t >> 6, lane = t & 63;
    const int fr   = lane & 15, h = lane >> 4;
    const int m0   = blockIdx.x * 128;
    constexpr int NT = N / 64;

    // A fragments: wave owns rows [wave*32, wave*32+32), full K=256
    bf16x8 aw[2][8];
    const unsigned short* Abase = A + (size_t)(m0 + wave * 32 + fr) * 256 + h * 8;
#pragma unroll
    for (int mi = 0; mi < 2; ++mi)
#pragma unroll
        for (int ks = 0; ks < 8; ++ks)
            aw[mi][ks] = *(const bf16x8*)(Abase + mi * 16 * 256 + ks * 32);

    auto stage = [&](int b, int nt) {
        const unsigned short* Wt = W + (size_t)nt * 64 * 256;
#pragma unroll
        for (int q = 0; q < 8; ++q) {
            const int d    = q * 4096 + t * 16;            // dest byte offset
            const int row  = d >> 9;
            const int colb = (d & 511) ^ ((row & 7) << 4); // swizzled source col
            gload16(Wt + (size_t)row * 256 + (colb >> 1),
                    &W_lds[b][(q * 4096 + wave * 1024) >> 1]);
        }
    };

    stage(0, 0);
    __syncthreads();

    for (int nt = 0; nt < NT; ++nt) {
        if (nt + 1 < NT) stage((nt + 1) & 1, nt + 1);   // prefetch next tile

        const char* buf = (const char*)W_lds[nt & 1];
        f32x4 acc[2][4] = {};
#pragma unroll
        for (int nj = 0; nj < 4; ++nj) {
            const int   wrow = nj * 16 + fr;
            const char* wb   = buf + wrow * 512;
            const int   swz  = (fr & 7) << 4;
            bf16x8 wf[8];
#pragma unroll
            for (int ks = 0; ks < 8; ++ks)
                wf[ks] = *(const bf16x8*)(wb + ((ks * 64 + h * 16) ^ swz));
#pragma unroll
            for (int ks = 0; ks < 8; ++ks) {
                acc[0][nj] = __builtin_amdgcn_mfma_f32_16x16x32_bf16(wf[ks], aw[0][ks], acc[0][nj], 0, 0, 0);
                acc[1][nj] = __builtin_amdgcn_mfma_f32_16x16x32_bf16(wf[ks], aw[1][ks], acc[1][nj], 0, 0, 0);
            }
        }

#pragma unroll
        for (int mi = 0; mi < 2; ++mi) {
            const int m = m0 + wave * 32 + mi * 16 + fr;
#pragma unroll
            for (int nj = 0; nj < 4; ++nj) {
                const int n = nt * 64 + nj * 16 + h * 4;
                const float4 bb = *(const float4*)&bias[n];
                float v0 = acc[mi][nj][0] + bb.x;
                float v1 = acc[mi][nj][1] + bb.y;
                float v2 = acc[mi][nj][2] + bb.z;
                float v3 = acc[mi][nj][3] + bb.w;
                if (EPI == 2) {
                    v0 = fast_gelu(v0); v1 = fast_gelu(v1);
                    v2 = fast_gelu(v2); v3 = fast_gelu(v3);
                }
                uint2 pk;
                pk.x = (unsigned int)f2bf(v0) | ((unsigned int)f2bf(v1) << 16);
                pk.y = (unsigned int)f2bf(v2) | ((unsigned int)f2bf(v3) << 16);
                *(uint2*)&Cout[(size_t)m * N + n] = pk;
            }
        }
        __syncthreads();   // prefetched tile landed; buffer swap safe
    }
}

// ---------------------------------------------------------------------------
// proj GEMM (K=256, N=256) + window-reverse/unshift scatter + residual +
// FUSED LayerNorm2. Writes x1 (fp32) to out and LN2(x1) (bf16) to ln2out.
// Row LN stats: lane holds 64/256 of a row -> local sum + shfl_xor(16,32).
// ---------------------------------------------------------------------------
__global__ __launch_bounds__(256, 2) void proj_ln2(const unsigned short* __restrict__ A,
                                                   const unsigned short* __restrict__ W,
                                                   const float* __restrict__ bias,
                                                   const float* __restrict__ resid,
                                                   const float* __restrict__ g2,
                                                   const float* __restrict__ b2,
                                                   float* __restrict__ out,
                                                   unsigned short* __restrict__ ln2out) {
    __shared__ unsigned short W_lds[2][64 * 256];

    const int t    = threadIdx.x;
    const int wave = t >> 6, lane = t & 63;
    const int fr   = lane & 15, h = lane >> 4;
    const int m0   = blockIdx.x * 128;

    bf16x8 aw[2][8];
    const unsigned short* Abase = A + (size_t)(m0 + wave * 32 + fr) * 256 + h * 8;
#pragma unroll
    for (int mi = 0; mi < 2; ++mi)
#pragma unroll
        for (int ks = 0; ks < 8; ++ks)
            aw[mi][ks] = *(const bf16x8*)(Abase + mi * 16 * 256 + ks * 32);

    auto stage = [&](int b, int nt) {
        const unsigned short* Wt = W + (size_t)nt * 64 * 256;
#pragma unroll
        for (int q = 0; q < 8; ++q) {
            const int d    = q * 4096 + t * 16;
            const int row  = d >> 9;
            const int colb = (d & 511) ^ ((row & 7) << 4);
            gload16(Wt + (size_t)row * 256 + (colb >> 1),
                    &W_lds[b][(q * 4096 + wave * 1024) >> 1]);
        }
    };

    stage(0, 0);
    __syncthreads();

    f32x4 acc[2][16] = {};   // [mi][nt*4+nj], static indexing only
    for (int nt = 0; nt < 4; ++nt) {
        if (nt < 3) stage((nt + 1) & 1, nt + 1);
        const char* buf = (const char*)W_lds[nt & 1];
#pragma unroll
        for (int nj = 0; nj < 4; ++nj) {
            const int   wrow = nj * 16 + fr;
            const char* wb   = buf + wrow * 512;
            const int   swz  = (fr & 7) << 4;
            bf16x8 wf[8];
#pragma unroll
            for (int ks = 0; ks < 8; ++ks)
                wf[ks] = *(const bf16x8*)(wb + ((ks * 64 + h * 16) ^ swz));
#pragma unroll
            for (int u = 0; u < 4; ++u) {
                // u indexes nt statically via the unrolled outer loop body below
            }
            switch (nt) {   // keep acc indices compile-time constant
            case 0:
#pragma unroll
                for (int ks = 0; ks < 8; ++ks) {
                    acc[0][0 + nj] = __builtin_amdgcn_mfma_f32_16x16x32_bf16(wf[ks], aw[0][ks], acc[0][0 + nj], 0, 0, 0);
                    acc[1][0 + nj] = __builtin_amdgcn_mfma_f32_16x16x32_bf16(wf[ks], aw[1][ks], acc[1][0 + nj], 0, 0, 0);
                } break;
            case 1:
#pragma unroll
                for (int ks = 0; ks < 8; ++ks) {
                    acc[0][4 + nj] = __builtin_amdgcn_mfma_f32_16x16x32_bf16(wf[ks], aw[0][ks], acc[0][4 + nj], 0, 0, 0);
                    acc[1][4 + nj] = __builtin_amdgcn_mfma_f32_16x16x32_bf16(wf[ks], aw[1][ks], acc[1][4 + nj], 0, 0, 0);
                } break;
            case 2:
#pragma unroll
                for (int ks = 0; ks < 8; ++ks) {
                    acc[0][8 + nj] = __builtin_amdgcn_mfma_f32_16x16x32_bf16(wf[ks], aw[0][ks], acc[0][8 + nj], 0, 0, 0);
                    acc[1][8 + nj] = __builtin_amdgcn_mfma_f32_16x16x32_bf16(wf[ks], aw[1][ks], acc[1][8 + nj], 0, 0, 0);
                } break;
            default:
#pragma unroll
                for (int ks = 0; ks < 8; ++ks) {
                    acc[0][12 + nj] = __builtin_amdgcn_mfma_f32_16x16x32_bf16(wf[ks], aw[0][ks], acc[0][12 + nj], 0, 0, 0);
                    acc[1][12 + nj] = __builtin_amdgcn_mfma_f32_16x16x32_bf16(wf[ks], aw[1][ks], acc[1][12 + nj], 0, 0, 0);
                } break;
            }
        }
        __syncthreads();
    }

#pragma unroll
    for (int mi = 0; mi < 2; ++mi) {
        const int m    = m0 + wave * 32 + mi * 16 + fr;
        const int bimg = m >> 14;
        const int rem  = m & 16383;
        const int win  = rem >> 6;
        const int tok  = rem & 63;
        const int hp = (win >> 4) * 8 + (tok >> 3);
        const int wp = (win & 15) * 8 + (tok & 7);
        const int ho = (hp + SS_) & (H_ - 1);
        const int wo = (wp + SS_) & (W_ - 1);
        const size_t drow = ((size_t)(bimg << 14) + ho * W_ + wo) * 256;

        float sum = 0.0f, ssum = 0.0f;
#pragma unroll
        for (int u = 0; u < 16; ++u) {
            const int n = (u >> 2) * 64 + (u & 3) * 16 + h * 4;
            const float4 bb = *(const float4*)&bias[n];
            const float4 r4 = *(const float4*)&resid[drow + n];
            float4 v;
            v.x = acc[mi][u][0] + bb.x + r4.x;
            v.y = acc[mi][u][1] + bb.y + r4.y;
            v.z = acc[mi][u][2] + bb.z + r4.z;
            v.w = acc[mi][u][3] + bb.w + r4.w;
            *(float4*)&out[drow + n] = v;
            sum  += v.x + v.y + v.z + v.w;
            ssum += v.x*v.x + v.y*v.y + v.z*v.z + v.w*v.w;
        }
        sum  += __shfl_xor(sum, 16, 64);  sum  += __shfl_xor(sum, 32, 64);
        ssum += __shfl_xor(ssum, 16, 64); ssum += __shfl_xor(ssum, 32, 64);
        const float mean = sum * (1.0f / 256.0f);
        const float rstd = rsqrtf(ssum * (1.0f / 256.0f) - mean * mean + 1e-5f);

#pragma unroll
        for (int u = 0; u < 16; ++u) {
            const int n = (u >> 2) * 64 + (u & 3) * 16 + h * 4;
            const float4 v  = *(const float4*)&out[drow + n];   // L1/L2-hot re-read
            const float4 gg = *(const float4*)&g2[n];
            const float4 bb = *(const float4*)&b2[n];
            uint2 pk;
            pk.x = (unsigned int)f2bf((v.x - mean) * rstd * gg.x + bb.x)
                 | ((unsigned int)f2bf((v.y - mean) * rstd * gg.y + bb.y) << 16);
            pk.y = (unsigned int)f2bf((v.z - mean) * rstd * gg.z + bb.z)
                 | ((unsigned int)f2bf((v.w - mean) * rstd * gg.w + bb.w) << 16);
            *(uint2*)&ln2out[drow + n] = pk;
        }
    }
}

// ---------------------------------------------------------------------------
// FC2 GEMM: out[M,256] += A[M,1024] @ W2[256,1024]^T + b2.
// 512 thr / 8 waves (2x4), BM=128, BN=256, BK=32, double-buffered LDS (48KB),
// 2-phase prefetch, ONE barrier per K-iter. 16B-slot XOR swizzle
// (slot = h ^ ((row>>1)&3)) applied on stage-source AND read (bijective).
// ---------------------------------------------------------------------------
__global__ __launch_bounds__(512, 4) void fc2_gemm(const unsigned short* __restrict__ A,
                                                   const unsigned short* __restrict__ W2,
                                                   const float* __restrict__ b2,
                                                   float* __restrict__ out) {
    __shared__ unsigned short lds[2][12288];   // A: 8KB, B: 16KB per buffer

    const int t    = threadIdx.x;
    const int wave = t >> 6, lane = t & 63;
    const int fr   = lane & 15, h = lane >> 4;
    const int wr   = wave >> 2, wc = wave & 3;
    const int m0   = blockIdx.x * 128;

    const int rb = t >> 2;                    // staging row 0..127
    const int cs = (t & 3) ^ ((rb >> 1) & 3); // swizzled source k-chunk

    auto stage = [&](int b, int kt) {
        gload16(A  + (size_t)(m0 + rb) * 1024 + kt + cs * 8,
                &lds[b][(wave * 1024) >> 1]);
        gload16(W2 + (size_t)rb * 1024 + kt + cs * 8,
                &lds[b][(8192 + wave * 1024) >> 1]);
        gload16(W2 + (size_t)(128 + rb) * 1024 + kt + cs * 8,
                &lds[b][(16384 + wave * 1024) >> 1]);
    };

    f32x4 acc[4][4] = {};

    stage(0, 0);
    __syncthreads();

    for (int it = 0; it < 32; ++it) {
        if (it + 1 < 32) stage((it + 1) & 1, (it + 1) * 32);

        const char* As = (const char*)lds[it & 1];
        const char* Bs = As + 8192;
        const int   sl = h ^ ((fr >> 1) & 3);   // row>>1 & 3 == fr>>1 & 3 (16-aligned bases)
        bf16x8 a[4], bfr[4];
#pragma unroll
        for (int mi = 0; mi < 4; ++mi) {
            const int r = wr * 64 + mi * 16 + fr;
            a[mi] = *(const bf16x8*)(As + r * 64 + sl * 16);
        }
#pragma unroll
        for (int nj = 0; nj < 4; ++nj) {
            const int r = wc * 64 + nj * 16 + fr;
            bfr[nj] = *(const bf16x8*)(Bs + r * 64 + sl * 16);
        }
#pragma unroll
        for (int mi = 0; mi < 4; ++mi)
#pragma unroll
            for (int nj = 0; nj < 4; ++nj)
                acc[mi][nj] = __builtin_amdgcn_mfma_f32_16x16x32_bf16(
                    bfr[nj], a[mi], acc[mi][nj], 0, 0, 0);
        __syncthreads();
    }

    float4 bv[4];
#pragma unroll
    for (int nj = 0; nj < 4; ++nj) bv[nj] = *(const float4*)&b2[wc * 64 + nj * 16 + h * 4];

#pragma unroll
    for (int mi = 0; mi < 4; ++mi) {
        const int m = m0 + wr * 64 + mi * 16 + fr;
#pragma unroll
        for (int nj = 0; nj < 4; ++nj) {
            const int n = wc * 64 + nj * 16 + h * 4;
            const size_t idx = (size_t)m * 256 + n;
            const float4 r4 = *(const float4*)&out[idx];
            float4 o;
            o.x = acc[mi][nj][0] + bv[nj].x + r4.x;
            o.y = acc[mi][nj][1] + bv[nj].y + r4.y;
            o.z = acc[mi][nj][2] + bv[nj].z + r4.z;
            o.w = acc[mi][nj][3] + bv[nj].w + r4.w;
            *(float4*)&out[idx] = o;
        }
    }
}

// ---------------------------------------------------------------------------
// MFMA windowed attention (unchanged — passing).
// ---------------------------------------------------------------------------
__device__ __forceinline__ int grp_(int p) { return p < (H_ - WS_) ? 0 : (p < (H_ - SS_) ? 1 : 2); }

__global__ __launch_bounds__(256) void attn_kernel(const unsigned short* __restrict__ qkv,
                                                   const float* __restrict__ rpb,
                                                   unsigned short* __restrict__ out) {
    __shared__ unsigned short P [4][64 * 72];
    __shared__ unsigned short Vt[4][32 * 72];
    __shared__ float rpb_s[232];

    const int t    = threadIdx.x;
    const int wid  = t >> 6, lane = t & 63;
    const int head = blockIdx.x & 7;
    const int win  = (blockIdx.x >> 3) * 4 + wid;
    const int fr   = lane & 15, h = lane >> 4;

    if (t < 225) rpb_s[t] = rpb[t * 8 + head];
    __syncthreads();

    const size_t qbase = (size_t)win * 64 * 768 + head * HD_;

    bf16x8 ak[4], bq[4];
#pragma unroll
    for (int ki = 0; ki < 4; ++ki)
        ak[ki] = *(const bf16x8*)&qkv[qbase + (size_t)(ki * 16 + fr) * 768 + 256 + h * 8];
#pragma unroll
    for (int qj = 0; qj < 4; ++qj)
        bq[qj] = *(const bf16x8*)&qkv[qbase + (size_t)(qj * 16 + fr) * 768 + h * 8];

    {
        const unsigned short* vrow = &qkv[qbase + (size_t)lane * 768 + 512];
#pragma unroll
        for (int dv = 0; dv < 32; dv += 8) {
            bf16x8 v8 = *(const bf16x8*)&vrow[dv];
#pragma unroll
            for (int j = 0; j < 8; ++j)
                Vt[wid][(dv + j) * 72 + lane] = ((unsigned short*)&v8)[j];
        }
    }

    f32x4 st[4][4] = {};
#pragma unroll
    for (int ki = 0; ki < 4; ++ki)
#pragma unroll
        for (int qj = 0; qj < 4; ++qj)
            st[ki][qj] = __builtin_amdgcn_mfma_f32_16x16x32_bf16(ak[ki], bq[qj], st[ki][qj], 0, 0, 0);

    const int wim = win & 255;
    const int whb = (wim >> 4) * 8, wwb = (wim & 15) * 8;
    const float qscale = 0.17677669529663687f;

#pragma unroll
    for (int qj = 0; qj < 4; ++qj) {
        const int q  = qj * 16 + fr;
        const int yq = q >> 3, xq = q & 7;
        const int gq = grp_(whb + yq) * 3 + grp_(wwb + xq);
        float s[16];
#pragma unroll
        for (int ki = 0; ki < 4; ++ki)
#pragma unroll
            for (int r = 0; r < 4; ++r) {
                const int k  = ki * 16 + h * 4 + r;
                const int yk = k >> 3, xk = k & 7;
                const int gk = grp_(whb + yk) * 3 + grp_(wwb + xk);
                float v = fmaf(st[ki][qj][r], qscale,
                               rpb_s[(yq - yk + 7) * 15 + (xq - xk + 7)]);
                if (gk != gq) v -= 100.0f;
                s[ki * 4 + r] = v;
            }
        float m = s[0];
#pragma unroll
        for (int i = 1; i < 16; ++i) m = fmaxf(m, s[i]);
        m = fmaxf(m, __shfl_xor(m, 16, 64));
        m = fmaxf(m, __shfl_xor(m, 32, 64));
        float sum = 0.0f;
#pragma unroll
        for (int i = 0; i < 16; ++i) { s[i] = __expf(s[i] - m); sum += s[i]; }
        sum += __shfl_xor(sum, 16, 64);
        sum += __shfl_xor(sum, 32, 64);
        const float rinv = __builtin_amdgcn_rcpf(sum);
#pragma unroll
        for (int ki = 0; ki < 4; ++ki)
#pragma unroll
            for (int rp = 0; rp < 4; rp += 2) {
                const unsigned int lo = f2bf(s[ki * 4 + rp]     * rinv);
                const unsigned int hi = f2bf(s[ki * 4 + rp + 1] * rinv);
                *(unsigned int*)&P[wid][q * 72 + ki * 16 + h * 4 + rp] = lo | (hi << 16);
            }
    }

    f32x4 oacc[4][2] = {};
#pragma unroll
    for (int ks = 0; ks < 2; ++ks) {
        bf16x8 pa[4], vb[2];
#pragma unroll
        for (int qi = 0; qi < 4; ++qi)
            pa[qi] = *(const bf16x8*)&P[wid][(qi * 16 + fr) * 72 + ks * 32 + h * 8];
#pragma unroll
        for (int nj = 0; nj < 2; ++nj)
            vb[nj] = *(const bf16x8*)&Vt[wid][(nj * 16 + fr) * 72 + ks * 32 + h * 8];
#pragma unroll
        for (int qi = 0; qi < 4; ++qi)
#pragma unroll
            for (int nj = 0; nj < 2; ++nj)
                oacc[qi][nj] = __builtin_amdgcn_mfma_f32_16x16x32_bf16(pa[qi], vb[nj], oacc[qi][nj], 0, 0, 0);
    }

#pragma unroll
    for (int qi = 0; qi < 4; ++qi)
#pragma unroll
        for (int nj = 0; nj < 2; ++nj)
#pragma unroll
            for (int r = 0; r < 4; ++r) {
                const int q = qi * 16 + h * 4 + r;
                const int d = nj * 16 + fr;
                out[((size_t)win * 64 + q) * C_ + head * HD_ + d] = f2bf(oacc[qi][nj][r]);
            }
}

// ---------------------------------------------------------------------------
extern "C" void kernel_launch(void* const* d_in, const int* in_sizes, int n_in,
                              void* d_out, int out_size, void* d_ws, size_t ws_size,
                              hipStream_t stream) {
    const float* x      = (const float*)d_in[0];
    const float* n1g    = (const float*)d_in[1];
    const float* n1b    = (const float*)d_in[2];
    const float* qkv_w  = (const float*)d_in[3];
    const float* qkv_b  = (const float*)d_in[4];
    const float* rpb    = (const float*)d_in[5];
    const float* proj_w = (const float*)d_in[6];
    const float* proj_b = (const float*)d_in[7];
    const float* n2g    = (const float*)d_in[8];
    const float* n2b    = (const float*)d_in[9];
    const float* fc1_w  = (const float*)d_in[10];
    const float* fc1_b  = (const float*)d_in[11];
    const float* fc2_w  = (const float*)d_in[12];
    const float* fc2_b  = (const float*)d_in[13];
    float* out = (float*)d_out;

    // workspace (bf16 elements), peak 322 MB (proven footprint):
    //   wq  2 MB weights | rA 64 MB (xw -> ln2out) | rB 256 MB:
    //   [0..192MB) qkv -> mlp1 ; [192..256MB) attn_o
    unsigned short* wq  = (unsigned short*)d_ws;
    unsigned short* rA  = wq + (1u << 20);
    unsigned short* rB  = rA + 33554432u;
    unsigned short* rB2 = rB + 100663296u;   // attn_o region

    unsigned short* qkv_wb  = wq;
    unsigned short* proj_wb = wq + 196608;
    unsigned short* fc1_wb  = wq + 262144;
    unsigned short* fc2_wb  = wq + 524288;

    cvt4<<<192, 256, 0, stream>>>(qkv_w,  qkv_wb,  196608);
    cvt4<<<64,  256, 0, stream>>>(proj_w, proj_wb, 65536);
    cvt4<<<256, 256, 0, stream>>>(fc1_w,  fc1_wb,  262144);
    cvt4<<<256, 256, 0, stream>>>(fc2_w,  fc2_wb,  262144);

    // 1. LN1 + cyclic shift + window partition  (x -> rA bf16)
    ln_kernel<1><<<MROWS / 4, 256, 0, stream>>>(x, n1g, n1b, rA);
    // 2. QKV projection (rA -> rB bf16)
    gemm_nloop<0, 768><<<MROWS / 128, 256, 0, stream>>>(rA, qkv_wb, qkv_b, rB);
    // 3. windowed attention (rB -> rB2 bf16)
    attn_kernel<<<(2048 / 4) * NH_, 256, 0, stream>>>(rB, rpb, rB2);
    // 4. proj + scatter + residual + fused LN2 (rB2 -> out fp32, rA bf16)
    proj_ln2<<<MROWS / 128, 256, 0, stream>>>(rB2, proj_wb, proj_b, x, n2g, n2b, out, rA);
    // 5. FC1 + fast GELU (rA -> rB bf16)
    gemm_nloop<2, 1024><<<MROWS / 128, 256, 0, stream>>>(rA, fc1_wb, fc1_b, rB);
    // 6. FC2 + residual (in-place on d_out fp32)
    fc2_gemm<<<MROWS / 128, 512, 0, stream>>>(rB, fc2_wb, fc2_b, out);
}